// Round 1
// 1088.499 us; speedup vs baseline: 1.3708x; 1.3708x over previous
//
#include <hip/hip_runtime.h>

#define TSTEPS 251
#define BT 8              // time-tile width
#define BLOCK 128         // threads per block = rows per block
#define INBUF (BLOCK * BT)   // 1024 floats per input buffer, LINEAR (no pad: global_load_lds dest)

// LDS: 6 linear input buffers (swizzled via pre-swizzled global source addresses)
//      + 1 padded output staging buffer.
// 6*1024*4 + 128*9*4 = 29184 B  -> 5 blocks/CU by LDS (grid supplies 4/CU avg)

__device__ __forceinline__ void gload4(const float* g, float* l) {
    // async global->LDS, 4 B per lane; LDS dest = wave-uniform base + lane*4
    __builtin_amdgcn_global_load_lds(
        (const __attribute__((address_space(1))) void*)g,
        (__attribute__((address_space(3))) void*)l,
        4, 0, 0);
}

__global__ __launch_bounds__(BLOCK) void gad_paths_kernel(
    const float* __restrict__ Z,
    const float* __restrict__ ua0,
    const float* __restrict__ ua1,
    const float* __restrict__ ub0,
    const float* __restrict__ ub1,
    const float* __restrict__ ug,
    float* __restrict__ out)
{
    __shared__ float lin[6 * INBUF];
    __shared__ float lout[BLOCK * (BT + 1)];

    const int tid  = threadIdx.x;
    const int lane = tid & 63;
    const int w    = tid >> 6;            // wave id (0/1), uniform per wave
    const int row0 = blockIdx.x * BLOCK;

    const float dt   = 0.004f;
    const float sqdt = sqrtf(0.004f);     // constant-folded, IEEE f32
    float s = 100.0f;                     // S0

    const float* __restrict__ srcs[6] = {Z, ua0, ua1, ub0, ub1, ug};

    // compute-phase swizzle constants: element (r,c) lives at lin[r*8 + (c ^ ((r>>2)&7))]
    // bank = 8*(r&3) + (c ^ ((r>>2)&7))  -> 2-way for 64 lanes at fixed c (free)
    const int q = (tid >> 2) & 7;
    const int b = tid * BT;

    for (int c0 = 0; c0 < TSTEPS; c0 += BT) {
        // ---- async staging: 6 arrays x (128 rows x 8 cols), all loads in flight ----
        #pragma unroll
        for (int a = 0; a < 6; ++a) {
            const float* __restrict__ src = srcs[a];
            #pragma unroll
            for (int k = 0; k < 8; ++k) {
                const int chunk = w * 8 + k;          // 64-float chunk in buffer
                const int fi    = chunk * 64 + lane;  // linear float index this lane fills
                const int r     = fi >> 3;            // row within block
                const int cp    = fi & 7;             // swizzled col slot
                int col = c0 + (cp ^ ((r >> 2) & 7)); // pre-swizzled source column
                col = col < TSTEPS ? col : (TSTEPS - 1);  // clamp for last tile (dup reads, unused)
                gload4(src + (size_t)(row0 + r) * TSTEPS + col,
                       &lin[a * INBUF + chunk * 64]); // wave-uniform LDS base
            }
        }
        __syncthreads();   // drains vmcnt -> whole tile resident

        // ---- per-row serial recurrence over this tile (reads swizzled slots) ----
        #pragma unroll
        for (int j = 0; j < BT; ++j) {
            const int t = c0 + j;                 // wave-uniform guard, no divergence
            if (t < TSTEPS) {
                if (t != 0) {                     // col 0 is the initial condition S0
                    const int o = b + (j ^ q);
                    float z  = lin[0 * INBUF + o] * sqdt;
                    float a0 = 0.05f + (0.15f - 0.05f) * lin[1 * INBUF + o];
                    float a1 = 0.10f + (0.30f - 0.10f) * lin[2 * INBUF + o];
                    float b0 = (0.05f - 0.00f) * lin[3 * INBUF + o];
                    float b1 = (0.10f - 0.00f) * lin[4 * INBUF + o];
                    float g  = 0.80f + (1.00f - 0.80f) * lin[5 * INBUF + o];
                    float base = a0 + a1 * fmaxf(s, 0.0f);
                    s = s + (b0 + b1 * s) * dt + __powf(base, g) * z;
                }
                lout[tid * (BT + 1) + j] = s;     // padded stride 9 -> 2-way, free
            }
        }
        __syncthreads();   // lout complete; lin free for next tile's async writes

        // ---- cooperative coalesced store of the output tile ----
        #pragma unroll
        for (int k = 0; k < BT; ++k) {
            const int p = tid + k * BLOCK;
            const int r = p >> 3;
            const int c = p & 7;
            if (c0 + c < TSTEPS)
                out[(size_t)(row0 + r) * TSTEPS + (c0 + c)] = lout[r * (BT + 1) + c];
        }
        // hazard check: next tile's gload4 writes lin only after this thread passed
        // bar2 (all compute reads of lin done); store reads lout, disjoint from lin.
    }
}

extern "C" void kernel_launch(void* const* d_in, const int* in_sizes, int n_in,
                              void* d_out, int out_size, void* d_ws, size_t ws_size,
                              hipStream_t stream)
{
    const float* Z   = (const float*)d_in[0];
    const float* ua0 = (const float*)d_in[1];
    const float* ua1 = (const float*)d_in[2];
    const float* ub0 = (const float*)d_in[3];
    const float* ub1 = (const float*)d_in[4];
    const float* ug  = (const float*)d_in[5];
    float* out = (float*)d_out;

    const int n_rows = in_sizes[0] / TSTEPS;   // 131072
    dim3 grid(n_rows / BLOCK), block(BLOCK);
    gad_paths_kernel<<<grid, block, 0, stream>>>(Z, ua0, ua1, ub0, ub1, ug, out);
}